// Round 3
// baseline (341.403 us; speedup 1.0000x reference)
//
#include <hip/hip_runtime.h>

// RQS (rational-quadratic spline) transform, 8192x2048 f32, K=8 bins.
// R2: VALU-bound per rocprof (VALUBusy 66%, HBM 25%). Cut VALU: single fast
// v_log_f32 for logdet (reuse rcp(den)), fast exp/log in table build,
// 2x grid for occupancy (32 waves/CU), NT loads/stores.
// R3: fix NT builtin type — use clang ext_vector float2, not HIP_vector_type.

constexpr int   KBINS = 8;
constexpr float TAILF = 3.0f;
constexpr float MINW  = 0.001f;
constexpr float MINH  = 0.001f;
constexpr float MIND  = 0.001f;
constexpr int   NROWS = 8192;
constexpr int   NDIM  = 2048;
constexpr int   NPAR  = 3 * KBINS - 1;  // 23
constexpr int   VEC   = 2;              // dims per thread (float2 loads/stores)
constexpr int   BLOCK = 256;
constexpr int   DIMS_PER_BLOCK = BLOCK * VEC;           // 512
constexpr int   BLOCKS_PER_ROW = NDIM / DIMS_PER_BLOCK; // 4
constexpr int   GROWS = 512;                            // parallel row walkers
constexpr int   ROWS_PER_WALK = NROWS / GROWS;          // 16

typedef float v2f __attribute__((ext_vector_type(2)));

__device__ __forceinline__ float rcp_fast(float x) {
    return __builtin_amdgcn_rcpf(x);  // v_rcp_f32, ~1 ulp
}

// fast softplus: max(x,0) + log(1+exp(-|x|)) with v_exp/v_log
__device__ __forceinline__ float softplus_fast(float x) {
    return fmaxf(x, 0.0f) + __logf(1.0f + __expf(-fabsf(x)));
}

// Build cw/ch (9 knots each) and dv (9 derivs) for one dim from its 23 params.
__device__ __forceinline__ void build_tables(const float* __restrict__ p,
                                             float* cw, float* ch, float* dv,
                                             float edge_deriv) {
    // widths -> cw knots
    {
        float u[KBINS];
        float m = p[0];
#pragma unroll
        for (int k = 1; k < KBINS; ++k) m = fmaxf(m, p[k]);
        float s = 0.0f;
#pragma unroll
        for (int k = 0; k < KBINS; ++k) { u[k] = __expf(p[k] - m); s += u[k]; }
        const float scale = (1.0f - MINW * KBINS) * rcp_fast(s);
        cw[0] = -TAILF;
        float acc = 0.0f;
#pragma unroll
        for (int k = 0; k < KBINS; ++k) {
            acc += MINW + scale * u[k];
            cw[k + 1] = fmaf(2.0f * TAILF, acc, -TAILF);
        }
        cw[KBINS] = TAILF;
    }
    // heights -> ch knots
    {
        const float* q = p + KBINS;
        float u[KBINS];
        float m = q[0];
#pragma unroll
        for (int k = 1; k < KBINS; ++k) m = fmaxf(m, q[k]);
        float s = 0.0f;
#pragma unroll
        for (int k = 0; k < KBINS; ++k) { u[k] = __expf(q[k] - m); s += u[k]; }
        const float scale = (1.0f - MINH * KBINS) * rcp_fast(s);
        ch[0] = -TAILF;
        float acc = 0.0f;
#pragma unroll
        for (int k = 0; k < KBINS; ++k) {
            acc += MINH + scale * u[k];
            ch[k + 1] = fmaf(2.0f * TAILF, acc, -TAILF);
        }
        ch[KBINS] = TAILF;
    }
    // derivatives (boundary padded so deriv == 1.0)
    dv[0] = edge_deriv;
    dv[KBINS] = edge_deriv;
#pragma unroll
    for (int k = 1; k < KBINS; ++k)
        dv[k] = MIND + softplus_fast(p[2 * KBINS + k - 1]);
}

__device__ __forceinline__ void rqs_eval(float x,
                                         const float* cw, const float* ch, const float* dv,
                                         float& o, float& ld) {
    const float xi = fminf(fmaxf(x, -TAILF), TAILF);
    // unrolled bin scan + value select (register cndmask chain)
    float icw = cw[0], ncw = cw[1];
    float ich = ch[0], nch = ch[1];
    float dlo = dv[0], dhi = dv[1];
#pragma unroll
    for (int k = 1; k < KBINS; ++k) {
        const bool c = xi >= cw[k];
        icw = c ? cw[k]     : icw;
        ncw = c ? cw[k + 1] : ncw;
        ich = c ? ch[k]     : ich;
        nch = c ? ch[k + 1] : nch;
        dlo = c ? dv[k]     : dlo;
        dhi = c ? dv[k + 1] : dhi;
    }
    const float iw  = ncw - icw;
    const float ih  = nch - ich;
    const float riw = rcp_fast(iw);
    const float delta = ih * riw;
    const float theta = (xi - icw) * riw;
    const float omt   = 1.0f - theta;
    const float t1m   = theta * omt;
    const float th2   = theta * theta;
    const float num   = ih * fmaf(delta, th2, dlo * t1m);
    const float den   = fmaf(dlo + dhi - 2.0f * delta, t1m, delta);
    const float rden  = rcp_fast(den);
    const float o_in  = fmaf(num, rden, ich);
    const float dn    = (delta * delta) *
                        fmaf(dhi, th2, fmaf(2.0f * delta, t1m, dlo * (omt * omt)));
    // log(dn) - 2 log(den) == log(dn * rden * rden): ONE fast log
    const float ld_in = __logf(dn * rden * rden);
    const bool inside = (x >= -TAILF) && (x <= TAILF);
    o  = inside ? o_in : x;
    ld = inside ? ld_in : 0.0f;
}

__global__ __launch_bounds__(BLOCK, 8)
void rqs_kernel(const float* __restrict__ inp,
                const float* __restrict__ params,
                float* __restrict__ out) {
    const int b        = blockIdx.x;
    const int colBlock = b & (BLOCKS_PER_ROW - 1);
    const int rowGroup = b / BLOCKS_PER_ROW;
    const int d0   = colBlock * DIMS_PER_BLOCK + (int)threadIdx.x * VEC;
    const int row0 = rowGroup * ROWS_PER_WALK;

    const float edge_deriv = MIND + softplus_fast(__logf(__expf(1.0f - MIND) - 1.0f));

    float cw[VEC][KBINS + 1], ch[VEC][KBINS + 1], dv[VEC][KBINS + 1];
#pragma unroll
    for (int v = 0; v < VEC; ++v)
        build_tables(params + (size_t)(d0 + v) * NPAR, cw[v], ch[v], dv[v], edge_deriv);

    const v2f* __restrict__ in2 = (const v2f*)inp;
    v2f* __restrict__ out2 = (v2f*)out;
    v2f* __restrict__ ld2  = (v2f*)(out + (size_t)NROWS * NDIM);

    size_t idx2 = ((size_t)row0 * NDIM + d0) >> 1;  // index in float2 units
#pragma unroll 4
    for (int r = 0; r < ROWS_PER_WALK; ++r) {
        const v2f xv = __builtin_nontemporal_load(&in2[idx2]);
        float o0, l0, o1, l1;
        rqs_eval(xv.x, cw[0], ch[0], dv[0], o0, l0);
        rqs_eval(xv.y, cw[1], ch[1], dv[1], o1, l1);
        v2f ov; ov.x = o0; ov.y = o1;
        v2f lv; lv.x = l0; lv.y = l1;
        __builtin_nontemporal_store(ov, &out2[idx2]);
        __builtin_nontemporal_store(lv, &ld2[idx2]);
        idx2 += NDIM / 2;
    }
}

extern "C" void kernel_launch(void* const* d_in, const int* in_sizes, int n_in,
                              void* d_out, int out_size, void* d_ws, size_t ws_size,
                              hipStream_t stream) {
    const float* inp    = (const float*)d_in[0];
    const float* params = (const float*)d_in[1];
    float* out          = (float*)d_out;
    rqs_kernel<<<BLOCKS_PER_ROW * GROWS, BLOCK, 0, stream>>>(inp, params, out);
}

// Round 4
// 200.369 us; speedup vs baseline: 1.7039x; 1.7039x over previous
//
#include <hip/hip_runtime.h>

// RQS (rational-quadratic spline) transform, 8192x2048 f32, K=8 bins.
// R1: 82us, VALU-bound (VALUBusy 66%, HBM 25%), occupancy 28%.
// R3 FAILED: __launch_bounds__(256,8) capped VGPR at 32 -> 54-float tables
//   spilled to scratch (FETCH 33->295MB), 204us. NT hints also killed L3 reuse.
// R4: revert cap to (256,4) [128 VGPR budget, no spill], plain loads/stores,
//   keep: 2048 blocks, single fast __logf logdet, fast exp/log table build.

constexpr int   KBINS = 8;
constexpr float TAILF = 3.0f;
constexpr float MINW  = 0.001f;
constexpr float MINH  = 0.001f;
constexpr float MIND  = 0.001f;
constexpr int   NROWS = 8192;
constexpr int   NDIM  = 2048;
constexpr int   NPAR  = 3 * KBINS - 1;  // 23
constexpr int   VEC   = 2;              // dims per thread (float2 loads/stores)
constexpr int   BLOCK = 256;
constexpr int   DIMS_PER_BLOCK = BLOCK * VEC;           // 512
constexpr int   BLOCKS_PER_ROW = NDIM / DIMS_PER_BLOCK; // 4
constexpr int   GROWS = 512;                            // parallel row walkers
constexpr int   ROWS_PER_WALK = NROWS / GROWS;          // 16

typedef float v2f __attribute__((ext_vector_type(2)));

__device__ __forceinline__ float rcp_fast(float x) {
    return __builtin_amdgcn_rcpf(x);  // v_rcp_f32, ~1 ulp
}

// fast softplus: max(x,0) + log(1+exp(-|x|)) with v_exp/v_log
__device__ __forceinline__ float softplus_fast(float x) {
    return fmaxf(x, 0.0f) + __logf(1.0f + __expf(-fabsf(x)));
}

// Build cw/ch (9 knots each) and dv (9 derivs) for one dim from its 23 params.
__device__ __forceinline__ void build_tables(const float* __restrict__ p,
                                             float* cw, float* ch, float* dv,
                                             float edge_deriv) {
    // widths -> cw knots
    {
        float u[KBINS];
        float m = p[0];
#pragma unroll
        for (int k = 1; k < KBINS; ++k) m = fmaxf(m, p[k]);
        float s = 0.0f;
#pragma unroll
        for (int k = 0; k < KBINS; ++k) { u[k] = __expf(p[k] - m); s += u[k]; }
        const float scale = (1.0f - MINW * KBINS) * rcp_fast(s);
        cw[0] = -TAILF;
        float acc = 0.0f;
#pragma unroll
        for (int k = 0; k < KBINS; ++k) {
            acc += MINW + scale * u[k];
            cw[k + 1] = fmaf(2.0f * TAILF, acc, -TAILF);
        }
        cw[KBINS] = TAILF;
    }
    // heights -> ch knots
    {
        const float* q = p + KBINS;
        float u[KBINS];
        float m = q[0];
#pragma unroll
        for (int k = 1; k < KBINS; ++k) m = fmaxf(m, q[k]);
        float s = 0.0f;
#pragma unroll
        for (int k = 0; k < KBINS; ++k) { u[k] = __expf(q[k] - m); s += u[k]; }
        const float scale = (1.0f - MINH * KBINS) * rcp_fast(s);
        ch[0] = -TAILF;
        float acc = 0.0f;
#pragma unroll
        for (int k = 0; k < KBINS; ++k) {
            acc += MINH + scale * u[k];
            ch[k + 1] = fmaf(2.0f * TAILF, acc, -TAILF);
        }
        ch[KBINS] = TAILF;
    }
    // derivatives (boundary padded so deriv == 1.0)
    dv[0] = edge_deriv;
    dv[KBINS] = edge_deriv;
#pragma unroll
    for (int k = 1; k < KBINS; ++k)
        dv[k] = MIND + softplus_fast(p[2 * KBINS + k - 1]);
}

__device__ __forceinline__ void rqs_eval(float x,
                                         const float* cw, const float* ch, const float* dv,
                                         float& o, float& ld) {
    const float xi = fminf(fmaxf(x, -TAILF), TAILF);
    // unrolled bin scan + value select (register cndmask chain)
    float icw = cw[0], ncw = cw[1];
    float ich = ch[0], nch = ch[1];
    float dlo = dv[0], dhi = dv[1];
#pragma unroll
    for (int k = 1; k < KBINS; ++k) {
        const bool c = xi >= cw[k];
        icw = c ? cw[k]     : icw;
        ncw = c ? cw[k + 1] : ncw;
        ich = c ? ch[k]     : ich;
        nch = c ? ch[k + 1] : nch;
        dlo = c ? dv[k]     : dlo;
        dhi = c ? dv[k + 1] : dhi;
    }
    const float iw  = ncw - icw;
    const float ih  = nch - ich;
    const float riw = rcp_fast(iw);
    const float delta = ih * riw;
    const float theta = (xi - icw) * riw;
    const float omt   = 1.0f - theta;
    const float t1m   = theta * omt;
    const float th2   = theta * theta;
    const float num   = ih * fmaf(delta, th2, dlo * t1m);
    const float den   = fmaf(dlo + dhi - 2.0f * delta, t1m, delta);
    const float rden  = rcp_fast(den);
    const float o_in  = fmaf(num, rden, ich);
    const float dn    = (delta * delta) *
                        fmaf(dhi, th2, fmaf(2.0f * delta, t1m, dlo * (omt * omt)));
    // log(dn) - 2 log(den) == log(dn * rden * rden): ONE fast log
    const float ld_in = __logf(dn * rden * rden);
    const bool inside = (x >= -TAILF) && (x <= TAILF);
    o  = inside ? o_in : x;
    ld = inside ? ld_in : 0.0f;
}

__global__ __launch_bounds__(BLOCK, 4)
void rqs_kernel(const float* __restrict__ inp,
                const float* __restrict__ params,
                float* __restrict__ out) {
    const int b        = blockIdx.x;
    const int colBlock = b & (BLOCKS_PER_ROW - 1);
    const int rowGroup = b / BLOCKS_PER_ROW;
    const int d0   = colBlock * DIMS_PER_BLOCK + (int)threadIdx.x * VEC;
    const int row0 = rowGroup * ROWS_PER_WALK;

    const float edge_deriv = MIND + softplus_fast(__logf(__expf(1.0f - MIND) - 1.0f));

    float cw[VEC][KBINS + 1], ch[VEC][KBINS + 1], dv[VEC][KBINS + 1];
#pragma unroll
    for (int v = 0; v < VEC; ++v)
        build_tables(params + (size_t)(d0 + v) * NPAR, cw[v], ch[v], dv[v], edge_deriv);

    const v2f* __restrict__ in2 = (const v2f*)inp;
    v2f* __restrict__ out2 = (v2f*)out;
    v2f* __restrict__ ld2  = (v2f*)(out + (size_t)NROWS * NDIM);

    size_t idx2 = ((size_t)row0 * NDIM + d0) >> 1;  // index in float2 units
#pragma unroll 4
    for (int r = 0; r < ROWS_PER_WALK; ++r) {
        const v2f xv = in2[idx2];
        float o0, l0, o1, l1;
        rqs_eval(xv.x, cw[0], ch[0], dv[0], o0, l0);
        rqs_eval(xv.y, cw[1], ch[1], dv[1], o1, l1);
        v2f ov; ov.x = o0; ov.y = o1;
        v2f lv; lv.x = l0; lv.y = l1;
        out2[idx2] = ov;
        ld2[idx2]  = lv;
        idx2 += NDIM / 2;
    }
}

extern "C" void kernel_launch(void* const* d_in, const int* in_sizes, int n_in,
                              void* d_out, int out_size, void* d_ws, size_t ws_size,
                              hipStream_t stream) {
    const float* inp    = (const float*)d_in[0];
    const float* params = (const float*)d_in[1];
    float* out          = (float*)d_out;
    rqs_kernel<<<BLOCKS_PER_ROW * GROWS, BLOCK, 0, stream>>>(inp, params, out);
}